// Round 1
// baseline (527.283 us; speedup 1.0000x reference)
//
#include <hip/hip_runtime.h>
#include <math.h>

// Problem constants
#define BB 2
#define CC 128
#define NN 4096            // D*H*W = 16*16*16
#define EE 46              // 16 + 15 + 15 neighbors
#define DS 64              // DSIM = PSIM = GDIM = 64
#define NROUNDS 3

// ---------------------------------------------------------------------------
// Kernel 1: build sorted neighbor table via 3-way merge of sorted axis lists.
// Node n=(i,j,k): axis-D list (incl self), axis-H list (excl self), axis-W
// list (excl self). All values distinct -> merge is unambiguous.
// Also zeroes colnorm_p (block 0).
__global__ void k_nbr(int* __restrict__ nbr, float* __restrict__ colnorm_p) {
    int n = blockIdx.x * blockDim.x + threadIdx.x;
    if (blockIdx.x == 0 && threadIdx.x < EE) colnorm_p[threadIdx.x] = 0.f;
    if (n >= NN) return;
    int i = n >> 8, j = (n >> 4) & 15, k = n & 15;
    int ia = 0, ib = 0, ic = 0;
    for (int e = 0; e < EE; ++e) {
        int va = (ia < 16) ? ia * 256 + j * 16 + k : 0x7fffffff;
        int jb = ib + (ib >= j ? 1 : 0);
        int vb = (ib < 15) ? i * 256 + jb * 16 + k : 0x7fffffff;
        int kc = ic + (ic >= k ? 1 : 0);
        int vc = (ic < 15) ? i * 256 + j * 16 + kc : 0x7fffffff;
        int v;
        if (va < vb && va < vc)      { v = va; ++ia; }
        else if (vb < vc)            { v = vb; ++ib; }
        else                         { v = vc; ++ic; }
        nbr[n * EE + e] = v;
    }
}

// ---------------------------------------------------------------------------
// Kernel 2: geo projections p_theta, p_phi  [N, 64]
__global__ void k_geo(const float* __restrict__ gtw, const float* __restrict__ gtb,
                      const float* __restrict__ gpw, const float* __restrict__ gpb,
                      float* __restrict__ p_theta, float* __restrict__ p_phi) {
    int idx = blockIdx.x * blockDim.x + threadIdx.x;
    if (idx >= NN * DS) return;
    int n = idx >> 6, s = idx & 63;
    int i = n >> 8, j = (n >> 4) & 15, k = n & 15;
    float p0 = i * (1.f / 15.f) - 0.5f;
    float p1 = j * (1.f / 15.f) - 0.5f;
    float p2 = k * (1.f / 15.f) - 0.5f;
    p_theta[idx] = p0 * gtw[s * 3 + 0] + p1 * gtw[s * 3 + 1] + p2 * gtw[s * 3 + 2] + gtb[s];
    p_phi[idx]   = p0 * gpw[s * 3 + 0] + p1 * gpw[s * 3 + 1] + p2 * gpw[s * 3 + 2] + gpb[s];
}

// ---------------------------------------------------------------------------
// Kernel 3: raw f_p[n][e] = dot64(p_theta[n], p_phi[nbr[n][e]]) + per-column
// sum-of-squares (block reduce + atomicAdd). grid = (16 node-chunks, 46 cols)
__global__ void k_fp(const int* __restrict__ nbr,
                     const float* __restrict__ pt, const float* __restrict__ pp,
                     float* __restrict__ fp_raw, float* __restrict__ colnorm_p) {
    __shared__ float red[4];
    int n = blockIdx.x * 256 + threadIdx.x;
    int e = blockIdx.y;
    int m = nbr[n * EE + e];
    const float* a = pt + n * DS;
    const float* b = pp + m * DS;
    float v = 0.f;
#pragma unroll
    for (int d = 0; d < DS; ++d) v += a[d] * b[d];
    fp_raw[n * EE + e] = v;
    float sq = v * v;
    for (int o = 32; o; o >>= 1) sq += __shfl_down(sq, o);
    if ((threadIdx.x & 63) == 0) red[threadIdx.x >> 6] = sq;
    __syncthreads();
    if (threadIdx.x == 0)
        atomicAdd(colnorm_p + e, red[0] + red[1] + red[2] + red[3]);
}

// Kernel 4: finalize f_p = relu(f_p / (1e-6 + sqrt(colnorm)))
__global__ void k_fpfin(float* __restrict__ fp, const float* __restrict__ colnorm_p) {
    int t = blockIdx.x * 256 + threadIdx.x;
    if (t >= NN * EE) return;
    int e = t % EE;
    float nrm = 1e-6f + sqrtf(colnorm_p[e]);
    float v = fp[t] / nrm;
    fp[t] = v > 0.f ? v : 0.f;
}

// ---------------------------------------------------------------------------
// Kernel 5: h[b][n][c] = x[b][c][n]
__global__ void k_hinit(const float* __restrict__ x, float* __restrict__ h) {
    int t = blockIdx.x * 256 + threadIdx.x;
    if (t >= BB * NN * CC) return;
    int c = t & (CC - 1);
    int n = (t >> 7) & (NN - 1);
    int b = t >> 19;
    h[t] = x[(b * CC + c) * NN + n];
}

// ---------------------------------------------------------------------------
// Per-round kernel A: fused theta/phi/G projections. One block per (b,n);
// 192 threads = 3 x 64 outputs; h row staged in LDS. Block 0 zeroes colnorm_f.
__global__ void k_proj(const float* __restrict__ h,
                       const float* __restrict__ thw, const float* __restrict__ thb,
                       const float* __restrict__ phw, const float* __restrict__ phb,
                       const float* __restrict__ gw,  const float* __restrict__ gb,
                       float* __restrict__ T, float* __restrict__ P, float* __restrict__ G,
                       float* __restrict__ colnorm_f) {
    int bn = blockIdx.x;
    int t = threadIdx.x;
    if (bn == 0 && t < BB * EE) colnorm_f[t] = 0.f;
    __shared__ float hs[CC];
    if (t < CC) hs[t] = h[bn * CC + t];
    __syncthreads();
    int sel = t >> 6, d = t & 63;
    const float* w; const float* bias; float* out;
    if (sel == 0)      { w = thw; bias = thb; out = T; }
    else if (sel == 1) { w = phw; bias = phb; out = P; }
    else               { w = gw;  bias = gb;  out = G; }
    float acc = bias[d];
    const float* wr = w + d * CC;
#pragma unroll
    for (int c = 0; c < CC; ++c) acc += hs[c] * wr[c];
    out[bn * DS + d] = acc;
}

// Per-round kernel B: f[b][n][e] = dot64(T[b,n], P[b,nbr[n,e]]) + per-(b,e)
// sum-of-squares. grid = (16 node-chunks, 46 cols, B)
__global__ void k_f(const int* __restrict__ nbr,
                    const float* __restrict__ T, const float* __restrict__ P,
                    float* __restrict__ f, float* __restrict__ colnorm_f) {
    __shared__ float red[4];
    int n = blockIdx.x * 256 + threadIdx.x;
    int e = blockIdx.y;
    int b = blockIdx.z;
    int m = nbr[n * EE + e];
    const float* a = T + (b * NN + n) * DS;
    const float* p = P + (b * NN + m) * DS;
    float v = 0.f;
#pragma unroll
    for (int d = 0; d < DS; ++d) v += a[d] * p[d];
    f[(b * NN + n) * EE + e] = v;
    float sq = v * v;
    for (int o = 32; o; o >>= 1) sq += __shfl_down(sq, o);
    if ((threadIdx.x & 63) == 0) red[threadIdx.x >> 6] = sq;
    __syncthreads();
    if (threadIdx.x == 0)
        atomicAdd(colnorm_f + b * EE + e, red[0] + red[1] + red[2] + red[3]);
}

// Per-round kernel C: per node (1 wave / 64 threads): normalize f, add f_p,
// softmax over 46, aggregate G over neighbors, project through r_w, residual.
__global__ void k_attn(const float* __restrict__ f, const float* __restrict__ colnorm_f,
                       const float* __restrict__ f_p, const int* __restrict__ nbr,
                       const float* __restrict__ Gx, const float* __restrict__ rw,
                       const float* __restrict__ rb, float* __restrict__ h) {
    int bn = blockIdx.x;
    int b = bn >> 12;          // bn / NN
    int n = bn & (NN - 1);
    int l = threadIdx.x;
    __shared__ float attn_s[EE];
    __shared__ int   nb_s[EE];
    __shared__ float y_s[DS];

    float fv = -INFINITY;
    if (l < EE) {
        float raw = f[bn * EE + l];
        float nrm = 1e-6f + sqrtf(colnorm_f[b * EE + l]);
        fv = raw / nrm + f_p[n * EE + l];
        nb_s[l] = nbr[n * EE + l];
    }
    float mx = fv;
    for (int o = 32; o; o >>= 1) mx = fmaxf(mx, __shfl_down(mx, o));
    mx = __shfl(mx, 0);
    float ex = (l < EE) ? expf(fv - mx) : 0.f;
    float sm = ex;
    for (int o = 32; o; o >>= 1) sm += __shfl_down(sm, o);
    sm = __shfl(sm, 0);
    if (l < EE) attn_s[l] = ex / sm;
    __syncthreads();

    // y[g] for g = l (64 lanes): coalesced reads of Gx rows
    float y = 0.f;
#pragma unroll 2
    for (int e = 0; e < EE; ++e) {
        y += attn_s[e] * Gx[(b * NN + nb_s[e]) * DS + l];
    }
    y_s[l] = y;
    __syncthreads();

    // delta[c] for c = l and c = l + 64
    float acc0 = rb[l], acc1 = rb[l + 64];
#pragma unroll
    for (int g = 0; g < DS; ++g) {
        float yv = y_s[g];
        acc0 += yv * rw[l * DS + g];
        acc1 += yv * rw[(l + 64) * DS + g];
    }
    h[bn * CC + l]      += acc0;
    h[bn * CC + l + 64] += acc1;
}

// ---------------------------------------------------------------------------
// Final: out[b][c][n] = h[b][n][c]
__global__ void k_out(const float* __restrict__ h, float* __restrict__ out) {
    int t = blockIdx.x * 256 + threadIdx.x;
    if (t >= BB * CC * NN) return;
    int n = t & (NN - 1);
    int c = (t >> 12) & (CC - 1);
    int b = t >> 19;
    out[t] = h[(b * NN + n) * CC + c];
}

// ---------------------------------------------------------------------------
extern "C" void kernel_launch(void* const* d_in, const int* in_sizes, int n_in,
                              void* d_out, int out_size, void* d_ws, size_t ws_size,
                              hipStream_t stream) {
    const float* x    = (const float*)d_in[0];
    const float* G_w  = (const float*)d_in[1];
    const float* G_b  = (const float*)d_in[2];
    const float* th_w = (const float*)d_in[3];
    const float* th_b = (const float*)d_in[4];
    const float* ph_w = (const float*)d_in[5];
    const float* ph_b = (const float*)d_in[6];
    const float* r_w  = (const float*)d_in[7];
    const float* r_b  = (const float*)d_in[8];
    const float* gt_w = (const float*)d_in[9];
    const float* gt_b = (const float*)d_in[10];
    const float* gp_w = (const float*)d_in[11];
    const float* gp_b = (const float*)d_in[12];
    float* out = (float*)d_out;

    // Workspace layout (byte offsets, 256-aligned)
    char* ws = (char*)d_ws;
    size_t off = 0;
    auto alloc = [&](size_t bytes) { char* p = ws + off; off = (off + bytes + 255) & ~size_t(255); return p; };
    int*   nbr       = (int*)  alloc(NN * EE * sizeof(int));       // 753664
    float* p_theta   = (float*)alloc(NN * DS * sizeof(float));     // 1 MiB
    float* p_phi     = (float*)alloc(NN * DS * sizeof(float));
    float* f_p       = (float*)alloc(NN * EE * sizeof(float));
    float* colnorm_p = (float*)alloc(EE * sizeof(float));
    float* h         = (float*)alloc((size_t)BB * NN * CC * sizeof(float)); // 4 MiB
    float* T         = (float*)alloc((size_t)BB * NN * DS * sizeof(float));
    float* P         = (float*)alloc((size_t)BB * NN * DS * sizeof(float));
    float* Gx        = (float*)alloc((size_t)BB * NN * DS * sizeof(float));
    float* f         = (float*)alloc((size_t)BB * NN * EE * sizeof(float));
    float* colnorm_f = (float*)alloc(BB * EE * sizeof(float));
    (void)ws_size; (void)in_sizes; (void)n_in; (void)out_size;

    // Precompute (neighbor table, geo attention prior)
    k_nbr<<<NN / 256, 256, 0, stream>>>(nbr, colnorm_p);
    k_geo<<<(NN * DS) / 256, 256, 0, stream>>>(gt_w, gt_b, gp_w, gp_b, p_theta, p_phi);
    k_fp<<<dim3(NN / 256, EE), 256, 0, stream>>>(nbr, p_theta, p_phi, f_p, colnorm_p);
    k_fpfin<<<(NN * EE + 255) / 256, 256, 0, stream>>>(f_p, colnorm_p);
    k_hinit<<<(BB * NN * CC) / 256, 256, 0, stream>>>(x, h);

    for (int r = 0; r < NROUNDS; ++r) {
        k_proj<<<BB * NN, 192, 0, stream>>>(h, th_w, th_b, ph_w, ph_b, G_w, G_b,
                                            T, P, Gx, colnorm_f);
        k_f<<<dim3(NN / 256, EE, BB), 256, 0, stream>>>(nbr, T, P, f, colnorm_f);
        k_attn<<<BB * NN, 64, 0, stream>>>(f, colnorm_f, f_p, nbr, Gx, r_w, r_b, h);
    }

    k_out<<<(BB * CC * NN) / 256, 256, 0, stream>>>(h, out);
}

// Round 2
// 256.126 us; speedup vs baseline: 2.0587x; 2.0587x over previous
//
#include <hip/hip_runtime.h>
#include <math.h>

// Problem constants
#define BB 2
#define CC 128
#define NN 4096            // D*H*W = 16*16*16
#define EE 46              // 16 + 15 + 15 neighbors
#define DS 64              // DSIM = PSIM = GDIM = 64
#define NROUNDS 3
#define CPAD 16            // dwords per colnorm counter (one 64B line each)

// ---------------------------------------------------------------------------
// Kernel 1: build sorted neighbor table via 3-way merge of sorted axis lists.
// Also zeroes padded colnorm_p (block 0).
__global__ void k_nbr(int* __restrict__ nbr, float* __restrict__ colnorm_p) {
    int n = blockIdx.x * blockDim.x + threadIdx.x;
    if (blockIdx.x == 0)
        for (int i = threadIdx.x; i < EE * CPAD; i += 256) colnorm_p[i] = 0.f;
    if (n >= NN) return;
    int i = n >> 8, j = (n >> 4) & 15, k = n & 15;
    int ia = 0, ib = 0, ic = 0;
    for (int e = 0; e < EE; ++e) {
        int va = (ia < 16) ? ia * 256 + j * 16 + k : 0x7fffffff;
        int jb = ib + (ib >= j ? 1 : 0);
        int vb = (ib < 15) ? i * 256 + jb * 16 + k : 0x7fffffff;
        int kc = ic + (ic >= k ? 1 : 0);
        int vc = (ic < 15) ? i * 256 + j * 16 + kc : 0x7fffffff;
        int v;
        if (va < vb && va < vc)      { v = va; ++ia; }
        else if (vb < vc)            { v = vb; ++ib; }
        else                         { v = vc; ++ic; }
        nbr[n * EE + e] = v;
    }
}

// ---------------------------------------------------------------------------
// Kernel 2: geo projections p_theta, p_phi  [N, 64]
__global__ void k_geo(const float* __restrict__ gtw, const float* __restrict__ gtb,
                      const float* __restrict__ gpw, const float* __restrict__ gpb,
                      float* __restrict__ p_theta, float* __restrict__ p_phi) {
    int idx = blockIdx.x * blockDim.x + threadIdx.x;
    if (idx >= NN * DS) return;
    int n = idx >> 6, s = idx & 63;
    int i = n >> 8, j = (n >> 4) & 15, k = n & 15;
    float p0 = i * (1.f / 15.f) - 0.5f;
    float p1 = j * (1.f / 15.f) - 0.5f;
    float p2 = k * (1.f / 15.f) - 0.5f;
    p_theta[idx] = p0 * gtw[s * 3 + 0] + p1 * gtw[s * 3 + 1] + p2 * gtw[s * 3 + 2] + gtb[s];
    p_phi[idx]   = p0 * gpw[s * 3 + 0] + p1 * gpw[s * 3 + 1] + p2 * gpw[s * 3 + 2] + gpb[s];
}

// ---------------------------------------------------------------------------
// k_f: f[b][n][e] = dot64(T[b,n], P[b,nbr[n,e]]) + padded per-(b,e) sumsq.
// Block = (16-node tile, b). 256 threads = 16 e-lanes (li) x 16 nodes (nl).
// Each thread handles e = li, li+16, li+32 (<46). Reused for the geo f_p pass
// with T=p_theta, P=p_phi, gridDim.y=1.
__global__ __launch_bounds__(256) void k_f(const int* __restrict__ nbr,
        const float* __restrict__ T, const float* __restrict__ P,
        float* __restrict__ f, float* __restrict__ colnorm) {
    __shared__ float4 ts4[16 * 17];      // 16 nodes x 64 dw, padded stride 68 dw
    __shared__ int nbr_s[16 * EE];
    const int t = threadIdx.x;
    const int b = blockIdx.y;
    const int tile = blockIdx.x;
    {
        int node = t >> 4, kc = t & 15;
        ts4[node * 17 + kc] = ((const float4*)T)[(size_t)(b * NN + tile * 16 + node) * 16 + kc];
    }
    for (int i = t; i < 16 * EE; i += 256) nbr_s[i] = nbr[tile * 16 * EE + i];
    __syncthreads();
    const int li = t >> 4, nl = t & 15;
    const int n = tile * 16 + nl;
    const float4* P4 = (const float4*)P;
    float sq[3] = {0.f, 0.f, 0.f};
#pragma unroll
    for (int s = 0; s < 3; ++s) {
        int e = li + 16 * s;
        if (e < EE) {
            int mm = nbr_s[nl * EE + e];
            const float4* pr = P4 + (size_t)(b * NN + mm) * 16;
            float acc = 0.f;
#pragma unroll
            for (int kc = 0; kc < 16; ++kc) {
                float4 a = ts4[nl * 17 + kc];
                float4 p = pr[kc];
                acc += a.x * p.x + a.y * p.y + a.z * p.z + a.w * p.w;
            }
            f[(size_t)(b * NN + n) * EE + e] = acc;
            sq[s] = acc * acc;
        }
    }
#pragma unroll
    for (int s = 0; s < 3; ++s) {
        float v = sq[s];
        v += __shfl_down(v, 8);
        v += __shfl_down(v, 4);
        v += __shfl_down(v, 2);
        v += __shfl_down(v, 1);
        if (nl == 0) {
            int e = li + 16 * s;
            if (e < EE) atomicAdd(colnorm + (b * EE + e) * CPAD, v);
        }
    }
}

// Kernel: finalize f_p = relu(f_p / (1e-6 + sqrt(colnorm)))
__global__ void k_fpfin(float* __restrict__ fp, const float* __restrict__ colnorm_p) {
    int t = blockIdx.x * 256 + threadIdx.x;
    if (t >= NN * EE) return;
    int e = t % EE;
    float nrm = 1e-6f + sqrtf(colnorm_p[e * CPAD]);
    float v = fp[t] / nrm;
    fp[t] = v > 0.f ? v : 0.f;
}

// ---------------------------------------------------------------------------
// LDS-tiled transpose: h[b][n][c] = x[b][c][n]. grid (64 n-tiles, 4 c-tiles, B)
__global__ __launch_bounds__(256) void k_hinit(const float* __restrict__ x,
                                               float* __restrict__ h) {
    __shared__ float xs[32][65];
    const int t = threadIdx.x;
    const int n0 = blockIdx.x * 64, c0 = blockIdx.y * 32, b = blockIdx.z;
    for (int q = t; q < 2048; q += 256) {
        int cl = q >> 6, nl = q & 63;
        xs[cl][nl] = x[(size_t)(b * CC + c0 + cl) * NN + n0 + nl];
    }
    __syncthreads();
    for (int q = t; q < 2048; q += 256) {
        int nl = q >> 5, cl = q & 31;
        h[(size_t)(b * NN + n0 + nl) * CC + c0 + cl] = xs[cl][nl];
    }
}

// ---------------------------------------------------------------------------
// k_proj: [8192 x 128] x [128 x 192]^T GEMM, f32 vector ALU.
// grid (128 row-tiles, 3 col-groups); col-group 0/1/2 -> theta/phi/G buffer.
// 64x64 tile, 4x4 register blocking, XOR-swizzled 64 KB LDS.
__global__ __launch_bounds__(256) void k_proj(const float* __restrict__ h,
        const float* __restrict__ thw, const float* __restrict__ thb,
        const float* __restrict__ phw, const float* __restrict__ phb,
        const float* __restrict__ gw,  const float* __restrict__ gb,
        float* __restrict__ T, float* __restrict__ P, float* __restrict__ G,
        float* __restrict__ colnorm_f) {
    __shared__ float4 smem[4096];        // 64 KB: hs4 [64][32] + ws4 [64][32]
    float4* hs4 = smem;
    float4* ws4 = smem + 2048;
    const int t = threadIdx.x;
    const int cg = blockIdx.y;
    const int row0 = blockIdx.x * 64;
    if (blockIdx.x == 0 && cg == 0)
        for (int i = t; i < BB * EE * CPAD; i += 256) colnorm_f[i] = 0.f;
    const float* w    = (cg == 0) ? thw : (cg == 1) ? phw : gw;
    const float* bias = (cg == 0) ? thb : (cg == 1) ? phb : gb;
    float* out        = (cg == 0) ? T   : (cg == 1) ? P   : G;
    const float4* h4 = (const float4*)h;
    const float4* w4 = (const float4*)w;
    for (int q = t; q < 2048; q += 256) {
        int row = q >> 5, kc = q & 31;
        hs4[row * 32 + (kc ^ (row & 31))] = h4[(size_t)(row0 + row) * 32 + kc];
        ws4[row * 32 + (kc ^ (row & 31))] = w4[q];
    }
    __syncthreads();
    const int rt = t >> 4, m = t & 15;
    float acc[4][4] = {};
    for (int kc = 0; kc < 32; ++kc) {
        float4 a[4], wv[4];
#pragma unroll
        for (int rr = 0; rr < 4; ++rr) {
            int r = rt * 4 + rr;
            a[rr] = hs4[r * 32 + (kc ^ (r & 31))];
        }
#pragma unroll
        for (int i = 0; i < 4; ++i) {
            int c = m + 16 * i;
            wv[i] = ws4[c * 32 + (kc ^ (c & 31))];
        }
#pragma unroll
        for (int rr = 0; rr < 4; ++rr)
#pragma unroll
            for (int i = 0; i < 4; ++i)
                acc[rr][i] += a[rr].x * wv[i].x + a[rr].y * wv[i].y
                            + a[rr].z * wv[i].z + a[rr].w * wv[i].w;
    }
#pragma unroll
    for (int i = 0; i < 4; ++i) {
        float bv = bias[m + 16 * i];
#pragma unroll
        for (int rr = 0; rr < 4; ++rr)
            out[(size_t)(row0 + rt * 4 + rr) * DS + m + 16 * i] = acc[rr][i] + bv;
    }
}

// ---------------------------------------------------------------------------
// k_attn: per node (1 wave): normalize f, add f_p, softmax over 46, aggregate
// G over neighbors, project through r_w (float4), residual into h.
__global__ __launch_bounds__(64) void k_attn(const float* __restrict__ f,
        const float* __restrict__ colnorm, const float* __restrict__ f_p,
        const int* __restrict__ nbr, const float* __restrict__ Gx,
        const float* __restrict__ rw, const float* __restrict__ rb,
        float* __restrict__ h) {
    const int bn = blockIdx.x, b = bn >> 12, n = bn & (NN - 1), l = threadIdx.x;
    __shared__ float attn_s[EE];
    __shared__ int   nb_s[EE];
    __shared__ __align__(16) float y_s[DS];

    float fv = -INFINITY;
    if (l < EE) {
        float nrm = 1e-6f + sqrtf(colnorm[(b * EE + l) * CPAD]);
        fv = f[(size_t)bn * EE + l] / nrm + f_p[n * EE + l];
        nb_s[l] = nbr[n * EE + l];
    }
    float mx = fv;
    for (int o = 32; o; o >>= 1) mx = fmaxf(mx, __shfl_down(mx, o));
    mx = __shfl(mx, 0);
    float ex = (l < EE) ? expf(fv - mx) : 0.f;
    float sm = ex;
    for (int o = 32; o; o >>= 1) sm += __shfl_down(sm, o);
    sm = __shfl(sm, 0);
    if (l < EE) attn_s[l] = ex / sm;
    __syncthreads();

    float y0 = 0.f, y1 = 0.f;
#pragma unroll
    for (int e = 0; e < EE; e += 2) {
        y0 += attn_s[e]     * Gx[(size_t)(b * NN + nb_s[e])     * DS + l];
        y1 += attn_s[e + 1] * Gx[(size_t)(b * NN + nb_s[e + 1]) * DS + l];
    }
    y_s[l] = y0 + y1;
    __syncthreads();

    const float4* rw4 = (const float4*)rw;
    const float4* ys4 = (const float4*)y_s;
    float acc0 = rb[l], acc1 = rb[l + 64];
#pragma unroll
    for (int g = 0; g < 16; ++g) {
        float4 yv = ys4[g];
        float4 w0 = rw4[l * 16 + g];
        float4 w1 = rw4[(l + 64) * 16 + g];
        acc0 += yv.x * w0.x + yv.y * w0.y + yv.z * w0.z + yv.w * w0.w;
        acc1 += yv.x * w1.x + yv.y * w1.y + yv.z * w1.z + yv.w * w1.w;
    }
    h[(size_t)bn * CC + l]      += acc0;
    h[(size_t)bn * CC + l + 64] += acc1;
}

// ---------------------------------------------------------------------------
// LDS-tiled transpose: out[b][c][n] = h[b][n][c]. grid (64, 4, B)
__global__ __launch_bounds__(256) void k_out(const float* __restrict__ h,
                                             float* __restrict__ out) {
    __shared__ float hs_[64][33];
    const int t = threadIdx.x;
    const int n0 = blockIdx.x * 64, c0 = blockIdx.y * 32, b = blockIdx.z;
    for (int q = t; q < 2048; q += 256) {
        int nl = q >> 5, cl = q & 31;
        hs_[nl][cl] = h[(size_t)(b * NN + n0 + nl) * CC + c0 + cl];
    }
    __syncthreads();
    for (int q = t; q < 2048; q += 256) {
        int cl = q >> 6, nl = q & 63;
        out[(size_t)(b * CC + c0 + cl) * NN + n0 + nl] = hs_[nl][cl];
    }
}

// ---------------------------------------------------------------------------
extern "C" void kernel_launch(void* const* d_in, const int* in_sizes, int n_in,
                              void* d_out, int out_size, void* d_ws, size_t ws_size,
                              hipStream_t stream) {
    const float* x    = (const float*)d_in[0];
    const float* G_w  = (const float*)d_in[1];
    const float* G_b  = (const float*)d_in[2];
    const float* th_w = (const float*)d_in[3];
    const float* th_b = (const float*)d_in[4];
    const float* ph_w = (const float*)d_in[5];
    const float* ph_b = (const float*)d_in[6];
    const float* r_w  = (const float*)d_in[7];
    const float* r_b  = (const float*)d_in[8];
    const float* gt_w = (const float*)d_in[9];
    const float* gt_b = (const float*)d_in[10];
    const float* gp_w = (const float*)d_in[11];
    const float* gp_b = (const float*)d_in[12];
    float* out = (float*)d_out;

    // Workspace layout (byte offsets, 256-aligned)
    char* ws = (char*)d_ws;
    size_t off = 0;
    auto alloc = [&](size_t bytes) { char* p = ws + off; off = (off + bytes + 255) & ~size_t(255); return p; };
    int*   nbr       = (int*)  alloc((size_t)NN * EE * sizeof(int));
    float* p_theta   = (float*)alloc((size_t)NN * DS * sizeof(float));
    float* p_phi     = (float*)alloc((size_t)NN * DS * sizeof(float));
    float* f_p       = (float*)alloc((size_t)NN * EE * sizeof(float));
    float* colnorm_p = (float*)alloc((size_t)EE * CPAD * sizeof(float));
    float* h         = (float*)alloc((size_t)BB * NN * CC * sizeof(float));
    float* T         = (float*)alloc((size_t)BB * NN * DS * sizeof(float));
    float* P         = (float*)alloc((size_t)BB * NN * DS * sizeof(float));
    float* Gx        = (float*)alloc((size_t)BB * NN * DS * sizeof(float));
    float* f         = (float*)alloc((size_t)BB * NN * EE * sizeof(float));
    float* colnorm_f = (float*)alloc((size_t)BB * EE * CPAD * sizeof(float));
    (void)ws_size; (void)in_sizes; (void)n_in; (void)out_size;

    // Precompute: neighbor table, geo prior (f_p), h transpose
    k_nbr<<<NN / 256, 256, 0, stream>>>(nbr, colnorm_p);
    k_geo<<<(NN * DS) / 256, 256, 0, stream>>>(gt_w, gt_b, gp_w, gp_b, p_theta, p_phi);
    k_f<<<dim3(NN / 16, 1), 256, 0, stream>>>(nbr, p_theta, p_phi, f_p, colnorm_p);
    k_fpfin<<<(NN * EE) / 256, 256, 0, stream>>>(f_p, colnorm_p);
    k_hinit<<<dim3(NN / 64, CC / 32, BB), 256, 0, stream>>>(x, h);

    for (int r = 0; r < NROUNDS; ++r) {
        k_proj<<<dim3(BB * NN / 64, 3), 256, 0, stream>>>(h, th_w, th_b, ph_w, ph_b,
                                                          G_w, G_b, T, P, Gx, colnorm_f);
        k_f<<<dim3(NN / 16, BB), 256, 0, stream>>>(nbr, T, P, f, colnorm_f);
        k_attn<<<BB * NN, 64, 0, stream>>>(f, colnorm_f, f_p, nbr, Gx, r_w, r_b, h);
    }

    k_out<<<dim3(NN / 64, CC / 32, BB), 256, 0, stream>>>(h, out);
}